// Round 10
// baseline (62.973 us; speedup 1.0000x reference)
//
#include <hip/hip_runtime.h>
#include <math.h>

#define DD  256
#define LKK 512
#define LQQ 256
#define BB  4

constexpr float TWO_LOG2E = 2.8853900817779268f;  // 2*log2(e)
constexpr float LOG2E     = 1.4426950408889634f;

__device__ __forceinline__ float fast_rcp(float x)  { return __builtin_amdgcn_rcpf(x); }
__device__ __forceinline__ float fast_exp2(float x) { return __builtin_amdgcn_exp2f(x); }

#define COMP(v,u) ((u)==0?(v).x:(u)==1?(v).y:(u)==2?(v).z:(v).w)

// EaT[b][e][k] = exp(2 * key[b,k,:] . W1[e,:])  (d-major / transposed)
// Eb [b*LQ+q][e] = exp(2 * query[b,q,:] . W2[e,:])  (row-major)
__global__ __launch_bounds__(256) void gemm_expk2(const float* __restrict__ key,
                                                  const float* __restrict__ query,
                                                  const float* __restrict__ W1,
                                                  const float* __restrict__ W2,
                                                  float* __restrict__ EaT,
                                                  float* __restrict__ Eb) {
  __shared__ float Xs[16][36];
  __shared__ float Ws[16][68];
  const int tid = threadIdx.x;
  const bool isK = blockIdx.x < (BB * LKK / 32);
  const float* __restrict__ X = isK ? key : query;
  const float* __restrict__ W = isK ? W1 : W2;
  const int m0 = (isK ? blockIdx.x : blockIdx.x - BB * LKK / 32) * 32;
  const int e0 = blockIdx.y * 64;

  const int r0 = (tid >> 4) << 1;   // 0..30
  const int c0 = (tid & 15) << 2;   // 0..60
  const int xr = tid >> 3, xc = (tid & 7) << 1;
  const int wr = tid >> 2, wc = (tid & 3) << 2;

  float2 xv = *(const float2*)&X[(m0 + xr) * DD + xc];
  float4 wv = *(const float4*)&W[(e0 + wr) * DD + wc];

  float acc[2][4] = {};
  for (int k0 = 0; k0 < DD; k0 += 16) {
    __syncthreads();
    Xs[xc][xr] = xv.x; Xs[xc + 1][xr] = xv.y;
    Ws[wc][wr] = wv.x; Ws[wc + 1][wr] = wv.y; Ws[wc + 2][wr] = wv.z; Ws[wc + 3][wr] = wv.w;
    __syncthreads();
    if (k0 + 16 < DD) {
      xv = *(const float2*)&X[(m0 + xr) * DD + k0 + 16 + xc];
      wv = *(const float4*)&W[(e0 + wr) * DD + k0 + 16 + wc];
    }
#pragma unroll
    for (int k = 0; k < 16; ++k) {
      const float2 a  = *(const float2*)&Xs[k][r0];
      const float4 bq = *(const float4*)&Ws[k][c0];
      acc[0][0] = fmaf(a.x, bq.x, acc[0][0]); acc[0][1] = fmaf(a.x, bq.y, acc[0][1]);
      acc[0][2] = fmaf(a.x, bq.z, acc[0][2]); acc[0][3] = fmaf(a.x, bq.w, acc[0][3]);
      acc[1][0] = fmaf(a.y, bq.x, acc[1][0]); acc[1][1] = fmaf(a.y, bq.y, acc[1][1]);
      acc[1][2] = fmaf(a.y, bq.z, acc[1][2]); acc[1][3] = fmaf(a.y, bq.w, acc[1][3]);
    }
  }
  if (isK) {
    const int b = m0 >> 9;
    const int kloc = (m0 & 511) + r0;
#pragma unroll
    for (int j = 0; j < 4; ++j) {
      float2 o;
      o.x = fast_exp2(acc[0][j] * TWO_LOG2E);
      o.y = fast_exp2(acc[1][j] * TWO_LOG2E);
      *(float2*)&EaT[b * (DD * LKK) + (e0 + c0 + j) * LKK + kloc] = o;
    }
  } else {
#pragma unroll
    for (int i = 0; i < 2; ++i) {
      float4 o;
      o.x = fast_exp2(acc[i][0] * TWO_LOG2E);
      o.y = fast_exp2(acc[i][1] * TWO_LOG2E);
      o.z = fast_exp2(acc[i][2] * TWO_LOG2E);
      o.w = fast_exp2(acc[i][3] * TWO_LOG2E);
      *(float4*)&Eb[(m0 + r0 + i) * DD + e0 + c0] = o;
    }
  }
}

// Fused: scores -> in-LDS softmax -> context. 512 blocks x 512 threads
// (2 blocks/CU, 16 waves/CU = 4/SIMD). Block = (b, 2 q-rows);
// phase-1 thread = ONE k-column, all 256 d (register-lean, hand-pipelined).
__global__ __launch_bounds__(512) void attn_fused(const float* __restrict__ EaT,
                                                  const float* __restrict__ Eb,
                                                  const float* __restrict__ vvec,
                                                  const float* __restrict__ value,
                                                  const int* __restrict__ mask,
                                                  float* __restrict__ ctx_out,
                                                  float* __restrict__ attn_out) {
  __shared__ float sc[2][LKK];       // 4 KB (scores, then probs)
  __shared__ float scr[8][2][DD];    // 16 KB (context k-partials)
  __shared__ float redm[2][4], reds[2][4];

  const int tid = threadIdx.x;
  const int bid = blockIdx.x;        // 0..511
  const int b  = bid >> 7;
  const int q0 = (bid & 127) << 1;
  const int k  = tid;                // 0..511

  const float* __restrict__ eb0 = &Eb[(b * LQQ + q0) * DD];
  const float* __restrict__ eb1 = eb0 + DD;

  // Sv = sum_d v[d] (uniform reads, scalar-cached)
  float Sv = 0.f;
#pragma unroll
  for (int d = 0; d < DD; d += 4) {
    const float4 vv = *(const float4*)&vvec[d];
    Sv += (vv.x + vv.y) + (vv.z + vv.w);
  }

  // ---- phase 1: scores for 1 k x 2 q, pipelined over d-chunks of 4 ----
  {
    const float* __restrict__ ea = &EaT[b * (DD * LKK) + k];
    float a0 = 0.f, a1 = 0.f;

    float c0 = ea[0 * LKK];
    float c1 = ea[1 * LKK];
    float c2 = ea[2 * LKK];
    float c3 = ea[3 * LKK];
    float4 ub0 = *(const float4*)&eb0[0];
    float4 ub1 = *(const float4*)&eb1[0];
    float4 uvv = *(const float4*)&vvec[0];

    for (int d = 0; d < DD - 4; d += 4) {
      // issue next chunk's loads first; latency hides under the 24 VALU ops below
      const float n0 = ea[(d + 4) * LKK];
      const float n1 = ea[(d + 5) * LKK];
      const float n2 = ea[(d + 6) * LKK];
      const float n3 = ea[(d + 7) * LKK];
      const float4 nb0 = *(const float4*)&eb0[d + 4];
      const float4 nb1 = *(const float4*)&eb1[d + 4];
      const float4 nvv = *(const float4*)&vvec[d + 4];
#pragma unroll
      for (int u = 0; u < 4; ++u) {
        const float a = (u == 0) ? c0 : (u == 1) ? c1 : (u == 2) ? c2 : c3;
        const float bq0 = COMP(ub0, u), bq1 = COMP(ub1, u), vd = COMP(uvv, u);
        a0 = fmaf(vd, fast_rcp(fmaf(a, bq0, 1.f)), a0);
        a1 = fmaf(vd, fast_rcp(fmaf(a, bq1, 1.f)), a1);
      }
      c0 = n0; c1 = n1; c2 = n2; c3 = n3;
      ub0 = nb0; ub1 = nb1; uvv = nvv;
    }
#pragma unroll
    for (int u = 0; u < 4; ++u) {
      const float a = (u == 0) ? c0 : (u == 1) ? c1 : (u == 2) ? c2 : c3;
      const float bq0 = COMP(ub0, u), bq1 = COMP(ub1, u), vd = COMP(uvv, u);
      a0 = fmaf(vd, fast_rcp(fmaf(a, bq0, 1.f)), a0);
      a1 = fmaf(vd, fast_rcp(fmaf(a, bq1, 1.f)), a1);
    }

    const float inv_scale = 0.0625f;  // 1/sqrt(256)
    float s0 = (Sv - 2.f * a0) * inv_scale;
    float s1 = (Sv - 2.f * a1) * inv_scale;
    const int row0 = (b * LQQ + q0) * LKK;
    if (mask[row0 + k] == 0)       s0 = -1e10f;
    if (mask[row0 + LKK + k] == 0) s1 = -1e10f;
    sc[0][k] = s0;
    sc[1][k] = s1;
  }
  __syncthreads();

  // ---- phase 2: softmax (4 waves per q-row, 2 elems per thread) ----
  {
    const int q = tid >> 8, j = tid & 255;
    const int w4 = (tid >> 6) & 3;
    float x0 = sc[q][j], x1 = sc[q][j + 256];
    float mx = fmaxf(x0, x1);
#pragma unroll
    for (int off = 32; off; off >>= 1) mx = fmaxf(mx, __shfl_xor(mx, off));
    if ((tid & 63) == 0) redm[q][w4] = mx;
    __syncthreads();
    mx = fmaxf(fmaxf(redm[q][0], redm[q][1]), fmaxf(redm[q][2], redm[q][3]));
    float p0 = fast_exp2((x0 - mx) * LOG2E);
    float p1 = fast_exp2((x1 - mx) * LOG2E);
    float sum = p0 + p1;
#pragma unroll
    for (int off = 32; off; off >>= 1) sum += __shfl_xor(sum, off);
    if ((tid & 63) == 0) reds[q][w4] = sum;
    __syncthreads();
    sum = (reds[q][0] + reds[q][1]) + (reds[q][2] + reds[q][3]);
    const float inv = fast_rcp(sum);
    p0 *= inv; p1 *= inv;
    const int arow = (b * LQQ + q0 + q) * LKK + j;
    attn_out[arow]       = p0;
    attn_out[arow + 256] = p1;
    sc[q][j]       = p0;
    sc[q][j + 256] = p1;
  }
  __syncthreads();

  // ---- phase 3: context (thread = k-eighth x float4 d, both q; LDS reduce) ----
  {
    const int kh = tid >> 6, dv = (tid & 63) << 2;
    const int kb = kh << 6;          // 64-k range
    float4 c0 = make_float4(0.f, 0.f, 0.f, 0.f);
    float4 c1 = make_float4(0.f, 0.f, 0.f, 0.f);
    const float* __restrict__ vb = &value[(b * LKK + kb) * DD + dv];
    for (int s = 0; s < 64; s += 4) {
      const float4 p0v = *(const float4*)&sc[0][kb + s];
      const float4 p1v = *(const float4*)&sc[1][kb + s];
#pragma unroll
      for (int u = 0; u < 4; ++u) {
        const float4 vv = *(const float4*)vb; vb += DD;
        const float a0 = COMP(p0v, u), a1 = COMP(p1v, u);
        c0.x = fmaf(a0, vv.x, c0.x); c0.y = fmaf(a0, vv.y, c0.y);
        c0.z = fmaf(a0, vv.z, c0.z); c0.w = fmaf(a0, vv.w, c0.w);
        c1.x = fmaf(a1, vv.x, c1.x); c1.y = fmaf(a1, vv.y, c1.y);
        c1.z = fmaf(a1, vv.z, c1.z); c1.w = fmaf(a1, vv.w, c1.w);
      }
    }
    *(float4*)&scr[kh][0][dv] = c0;
    *(float4*)&scr[kh][1][dv] = c1;
  }
  __syncthreads();

  if (tid < 128) {
    const int qq = tid >> 6, d4 = (tid & 63) << 2;
    float4 s4 = make_float4(0.f, 0.f, 0.f, 0.f);
#pragma unroll
    for (int kh2 = 0; kh2 < 8; ++kh2) {
      const float4 rr = *(const float4*)&scr[kh2][qq][d4];
      s4.x += rr.x; s4.y += rr.y; s4.z += rr.z; s4.w += rr.w;
    }
    *(float4*)&ctx_out[(b * LQQ + q0 + qq) * DD + d4] = s4;
  }
}

extern "C" void kernel_launch(void* const* d_in, const int* in_sizes, int n_in,
                              void* d_out, int out_size, void* d_ws, size_t ws_size,
                              hipStream_t stream) {
  const float* query = (const float*)d_in[0];
  const float* key   = (const float*)d_in[1];
  const float* value = (const float*)d_in[2];
  const float* W1    = (const float*)d_in[3];
  const float* W2    = (const float*)d_in[4];
  const float* v     = (const float*)d_in[5];
  const int*   mask  = (const int*)d_in[6];

  float* out      = (float*)d_out;
  float* ctx_out  = out;                       // [B, LQ, D]
  float* attn_out = out + BB * LQQ * DD;       // [B, LQ, LK]

  float* EaT = (float*)d_ws;                   // [B][D][LK] = 2 MB
  float* Eb  = EaT + BB * DD * LKK;            // [B*LQ][D]  = 1 MB

  dim3 g1(BB * LKK / 32 + BB * LQQ / 32, DD / 64);   // (96, 4)
  gemm_expk2<<<g1, 256, 0, stream>>>(key, query, W1, W2, EaT, Eb);

  attn_fused<<<512, 512, 0, stream>>>(EaT, Eb, v, value, mask, ctx_out, attn_out);
}

// Round 11
// 55.846 us; speedup vs baseline: 1.1276x; 1.1276x over previous
//
#include <hip/hip_runtime.h>
#include <math.h>

#define DD  256
#define LKK 512
#define LQQ 256
#define BB  4

constexpr float TWO_LOG2E = 2.8853900817779268f;  // 2*log2(e)
constexpr float LOG2E     = 1.4426950408889634f;
constexpr float CLAMPV    = 1e8f;                  // cap 1+Ea*Eb: tanh err ~2e-8, den<=1e32

__device__ __forceinline__ float fast_rcp(float x)  { return __builtin_amdgcn_rcpf(x); }
__device__ __forceinline__ float fast_exp2(float x) { return __builtin_amdgcn_exp2f(x); }

#define COMP(v,u) ((u)==0?(v).x:(u)==1?(v).y:(u)==2?(v).z:(v).w)

// EaT[b][e][k] = exp(2 * key[b,k,:] . W1[e,:])  (d-major / transposed)
// Eb [b*LQ+q][e] = exp(2 * query[b,q,:] . W2[e,:])  (row-major)
// 32x32 tiles, 8-way e-split: 768 blocks (3/CU) vs old 96 (0.375/CU).
__global__ __launch_bounds__(256) void gemm_expk2(const float* __restrict__ key,
                                                  const float* __restrict__ query,
                                                  const float* __restrict__ W1,
                                                  const float* __restrict__ W2,
                                                  float* __restrict__ EaT,
                                                  float* __restrict__ Eb) {
  __shared__ float Xs[16][36];
  __shared__ float Ws[16][36];
  const int tid = threadIdx.x;
  const bool isK = blockIdx.x < (BB * LKK / 32);   // 64 key-blocks, 32 query-blocks
  const float* __restrict__ X = isK ? key : query;
  const float* __restrict__ W = isK ? W1 : W2;
  const int m0 = (isK ? blockIdx.x : blockIdx.x - BB * LKK / 32) * 32;
  const int e0 = blockIdx.y * 32;

  const int r0 = (tid >> 4) << 1;   // 0..30
  const int c0 = (tid & 15) << 1;   // 0..30
  const int xr = tid >> 3, xc = (tid & 7) << 1;   // 32 rows x 16 k via float2

  float2 xv = *(const float2*)&X[(m0 + xr) * DD + xc];
  float2 wv = *(const float2*)&W[(e0 + xr) * DD + xc];

  float acc[2][2] = {};
  for (int k0 = 0; k0 < DD; k0 += 16) {
    __syncthreads();
    Xs[xc][xr] = xv.x; Xs[xc + 1][xr] = xv.y;
    Ws[xc][xr] = wv.x; Ws[xc + 1][xr] = wv.y;
    __syncthreads();
    if (k0 + 16 < DD) {   // prefetch next k-tile
      xv = *(const float2*)&X[(m0 + xr) * DD + k0 + 16 + xc];
      wv = *(const float2*)&W[(e0 + xr) * DD + k0 + 16 + xc];
    }
#pragma unroll
    for (int k = 0; k < 16; ++k) {
      const float2 a  = *(const float2*)&Xs[k][r0];
      const float2 bq = *(const float2*)&Ws[k][c0];
      acc[0][0] = fmaf(a.x, bq.x, acc[0][0]); acc[0][1] = fmaf(a.x, bq.y, acc[0][1]);
      acc[1][0] = fmaf(a.y, bq.x, acc[1][0]); acc[1][1] = fmaf(a.y, bq.y, acc[1][1]);
    }
  }
  if (isK) {
    const int b = m0 >> 9;
    const int kloc = (m0 & 511) + r0;
#pragma unroll
    for (int j = 0; j < 2; ++j) {
      float2 o;
      o.x = fast_exp2(acc[0][j] * TWO_LOG2E);
      o.y = fast_exp2(acc[1][j] * TWO_LOG2E);
      *(float2*)&EaT[b * (DD * LKK) + (e0 + c0 + j) * LKK + kloc] = o;
    }
  } else {
#pragma unroll
    for (int i = 0; i < 2; ++i) {
      float2 o;
      o.x = fast_exp2(acc[i][0] * TWO_LOG2E);
      o.y = fast_exp2(acc[i][1] * TWO_LOG2E);
      *(float2*)&Eb[(m0 + r0 + i) * DD + e0 + c0] = o;
    }
  }
}

// One quad = sum_{i=0..3} v_i/A_i with ONE rcp:
//   [(v0*B+v1*A)*CD + (v2*D+v3*C)*AB] / (AB*CD),  A..D = min(1+Ea*Eb, CLAMPV)
#define QUAD(CX, UB, ACC) do {                                        \
    const float A_  = fminf(fmaf(c0.CX, (UB).x, 1.f), CLAMPV);        \
    const float B_  = fminf(fmaf(c1.CX, (UB).y, 1.f), CLAMPV);        \
    const float C_  = fminf(fmaf(c2.CX, (UB).z, 1.f), CLAMPV);        \
    const float D_  = fminf(fmaf(c3.CX, (UB).w, 1.f), CLAMPV);        \
    const float AB_ = A_ * B_, CD_ = C_ * D_;                         \
    const float t1_ = fmaf(uvv.y, A_, uvv.x * B_);                    \
    const float t2_ = fmaf(uvv.w, C_, uvv.z * D_);                    \
    const float nm_ = fmaf(t1_, CD_, t2_ * AB_);                      \
    ACC = fmaf(nm_, fast_rcp(AB_ * CD_), ACC);                        \
  } while (0)

// Fused: quad-rcp scores -> in-LDS softmax -> context. 512 blocks x 256 thr
// (R9 geometry: block = (b, 2 q-rows), thread = 2 k-cols x 2 q, all 256 d).
__global__ __launch_bounds__(256) void attn_fused(const float* __restrict__ EaT,
                                                  const float* __restrict__ Eb,
                                                  const float* __restrict__ vvec,
                                                  const float* __restrict__ value,
                                                  const int* __restrict__ mask,
                                                  float* __restrict__ ctx_out,
                                                  float* __restrict__ attn_out) {
  __shared__ float sc[2][LKK];       // 4 KB (scores, then probs)
  __shared__ float scr[4][2][DD];    // 8 KB (context k-partials)
  __shared__ float redm[2][2], reds[2][2];

  const int tid = threadIdx.x;
  const int bid = blockIdx.x;        // 0..511
  const int b  = bid >> 7;
  const int q0 = (bid & 127) << 1;
  const int k2 = tid << 1;           // 0..510

  const float* __restrict__ eb0 = &Eb[(b * LQQ + q0) * DD];
  const float* __restrict__ eb1 = eb0 + DD;

  // ---- phase 1: scores (2k x 2q), pipelined d-chunks of 4, quad-rcp ----
  {
    const float* __restrict__ ea = &EaT[b * (DD * LKK) + k2];
    float a00 = 0.f, a01 = 0.f, a10 = 0.f, a11 = 0.f;  // [k-lane][q]
    float Sv = 0.f;

    float2 c0 = *(const float2*)&ea[0 * LKK];
    float2 c1 = *(const float2*)&ea[1 * LKK];
    float2 c2 = *(const float2*)&ea[2 * LKK];
    float2 c3 = *(const float2*)&ea[3 * LKK];
    float4 ub0 = *(const float4*)&eb0[0];
    float4 ub1 = *(const float4*)&eb1[0];
    float4 uvv = *(const float4*)&vvec[0];

    for (int d = 0; d < DD - 4; d += 4) {
      // issue next chunk's loads first; latency hides under the quads below
      const float2 n0 = *(const float2*)&ea[(d + 4) * LKK];
      const float2 n1 = *(const float2*)&ea[(d + 5) * LKK];
      const float2 n2 = *(const float2*)&ea[(d + 6) * LKK];
      const float2 n3 = *(const float2*)&ea[(d + 7) * LKK];
      const float4 nb0 = *(const float4*)&eb0[d + 4];
      const float4 nb1 = *(const float4*)&eb1[d + 4];
      const float4 nvv = *(const float4*)&vvec[d + 4];
      Sv += (uvv.x + uvv.y) + (uvv.z + uvv.w);
      QUAD(x, ub0, a00);
      QUAD(y, ub0, a10);
      QUAD(x, ub1, a01);
      QUAD(y, ub1, a11);
      c0 = n0; c1 = n1; c2 = n2; c3 = n3;
      ub0 = nb0; ub1 = nb1; uvv = nvv;
    }
    // epilogue chunk (d = 252)
    Sv += (uvv.x + uvv.y) + (uvv.z + uvv.w);
    QUAD(x, ub0, a00);
    QUAD(y, ub0, a10);
    QUAD(x, ub1, a01);
    QUAD(y, ub1, a11);

    const float inv_scale = 0.0625f;  // 1/sqrt(256)
    float2 s0, s1;                    // per q-row, (k2, k2+1)
    s0.x = (Sv - 2.f * a00) * inv_scale;
    s0.y = (Sv - 2.f * a10) * inv_scale;
    s1.x = (Sv - 2.f * a01) * inv_scale;
    s1.y = (Sv - 2.f * a11) * inv_scale;
    const int row0 = (b * LQQ + q0) * LKK + k2;
    const int2 m0 = *(const int2*)&mask[row0];
    const int2 m1 = *(const int2*)&mask[row0 + LKK];
    if (m0.x == 0) s0.x = -1e10f;
    if (m0.y == 0) s0.y = -1e10f;
    if (m1.x == 0) s1.x = -1e10f;
    if (m1.y == 0) s1.y = -1e10f;
    *(float2*)&sc[0][k2] = s0;
    *(float2*)&sc[1][k2] = s1;
  }
  __syncthreads();

  // ---- phase 2: softmax (threads 0..127 -> q=0, 128..255 -> q=1) ----
  {
    const int q = tid >> 7, j = tid & 127;
    const int w2 = (tid >> 6) & 1;
    float x0 = sc[q][j], x1 = sc[q][j + 128], x2 = sc[q][j + 256], x3 = sc[q][j + 384];
    float mx = fmaxf(fmaxf(x0, x1), fmaxf(x2, x3));
#pragma unroll
    for (int off = 32; off; off >>= 1) mx = fmaxf(mx, __shfl_xor(mx, off));
    if ((tid & 63) == 0) redm[q][w2] = mx;
    __syncthreads();
    mx = fmaxf(redm[q][0], redm[q][1]);
    float p0 = fast_exp2((x0 - mx) * LOG2E);
    float p1 = fast_exp2((x1 - mx) * LOG2E);
    float p2 = fast_exp2((x2 - mx) * LOG2E);
    float p3 = fast_exp2((x3 - mx) * LOG2E);
    float sum = (p0 + p1) + (p2 + p3);
#pragma unroll
    for (int off = 32; off; off >>= 1) sum += __shfl_xor(sum, off);
    if ((tid & 63) == 0) reds[q][w2] = sum;
    __syncthreads();
    sum = reds[q][0] + reds[q][1];
    const float inv = fast_rcp(sum);
    p0 *= inv; p1 *= inv; p2 *= inv; p3 *= inv;
    const int arow = (b * LQQ + q0 + q) * LKK + j;
    attn_out[arow]       = p0;
    attn_out[arow + 128] = p1;
    attn_out[arow + 256] = p2;
    attn_out[arow + 384] = p3;
    sc[q][j]       = p0;
    sc[q][j + 128] = p1;
    sc[q][j + 256] = p2;
    sc[q][j + 384] = p3;
  }
  __syncthreads();

  // ---- phase 3: context (thread = k-quarter x float4 d, both q; LDS reduce) ----
  {
    const int kh = tid >> 6, dv = (tid & 63) << 2;
    const int kb = kh << 7;          // 128-k range
    float4 c0 = make_float4(0.f, 0.f, 0.f, 0.f);
    float4 c1 = make_float4(0.f, 0.f, 0.f, 0.f);
    const float* __restrict__ vb = &value[(b * LKK + kb) * DD + dv];
    for (int s = 0; s < 128; s += 4) {
      const float4 p0v = *(const float4*)&sc[0][kb + s];
      const float4 p1v = *(const float4*)&sc[1][kb + s];
#pragma unroll
      for (int u = 0; u < 4; ++u) {
        const float4 vv = *(const float4*)vb; vb += DD;
        const float a0 = COMP(p0v, u), a1 = COMP(p1v, u);
        c0.x = fmaf(a0, vv.x, c0.x); c0.y = fmaf(a0, vv.y, c0.y);
        c0.z = fmaf(a0, vv.z, c0.z); c0.w = fmaf(a0, vv.w, c0.w);
        c1.x = fmaf(a1, vv.x, c1.x); c1.y = fmaf(a1, vv.y, c1.y);
        c1.z = fmaf(a1, vv.z, c1.z); c1.w = fmaf(a1, vv.w, c1.w);
      }
    }
    *(float4*)&scr[kh][0][dv] = c0;
    *(float4*)&scr[kh][1][dv] = c1;
  }
  __syncthreads();

  if (tid < 128) {
    const int qq = tid >> 6, d4 = (tid & 63) << 2;
    float4 s4 = make_float4(0.f, 0.f, 0.f, 0.f);
#pragma unroll
    for (int kh2 = 0; kh2 < 4; ++kh2) {
      const float4 rr = *(const float4*)&scr[kh2][qq][d4];
      s4.x += rr.x; s4.y += rr.y; s4.z += rr.z; s4.w += rr.w;
    }
    *(float4*)&ctx_out[(b * LQQ + q0 + qq) * DD + d4] = s4;
  }
}

extern "C" void kernel_launch(void* const* d_in, const int* in_sizes, int n_in,
                              void* d_out, int out_size, void* d_ws, size_t ws_size,
                              hipStream_t stream) {
  const float* query = (const float*)d_in[0];
  const float* key   = (const float*)d_in[1];
  const float* value = (const float*)d_in[2];
  const float* W1    = (const float*)d_in[3];
  const float* W2    = (const float*)d_in[4];
  const float* v     = (const float*)d_in[5];
  const int*   mask  = (const int*)d_in[6];

  float* out      = (float*)d_out;
  float* ctx_out  = out;                       // [B, LQ, D]
  float* attn_out = out + BB * LQQ * DD;       // [B, LQ, LK]

  float* EaT = (float*)d_ws;                   // [B][D][LK] = 2 MB
  float* Eb  = EaT + BB * DD * LKK;            // [B*LQ][D]  = 1 MB

  dim3 g1(BB * LKK / 32 + BB * LQQ / 32, DD / 32);   // (96, 8) = 768 blocks
  gemm_expk2<<<g1, 256, 0, stream>>>(key, query, W1, W2, EaT, Eb);

  attn_fused<<<512, 256, 0, stream>>>(EaT, Eb, v, value, mask, ctx_out, attn_out);
}